// Round 6
// baseline (281.868 us; speedup 1.0000x reference)
//
#include <hip/hip_runtime.h>
#include <math.h>

#define T_STEPS  512
#define N_ENVS   256
#define STATE    64
#define HID      128
#define NTHREADS 512   // 8 waves
#define XPAD     72    // xh row stride in f16 (64 + 8 pad: breaks 16-way bank conflict)

typedef _Float16 half8   __attribute__((ext_vector_type(8)));
typedef _Float16 half4_t __attribute__((ext_vector_type(4)));
typedef float    floatx4 __attribute__((ext_vector_type(4)));

// Raw workgroup barrier: LDS visibility only (lgkmcnt), NO vmcnt/expcnt drain.
#define BAR() asm volatile("s_waitcnt lgkmcnt(0)\n\ts_barrier" ::: "memory")

// v_exp_f32 is natively 2^x. Weights are pre-scaled into the exp2 domain.
__device__ __forceinline__ float fexp2(float v) {
    float r;
    asm("v_exp_f32 %0, %1" : "=v"(r) : "v"(v));
    return r;
}
// 2^(-|v|) with free source modifiers (no explicit neg/abs VALU op).
__device__ __forceinline__ float fexp2_nabs(float v) {
    float r;
    asm("v_exp_f32 %0, -|%1|" : "=v"(r) : "v"(v));
    return r;
}

// One block per env, 8 waves. Wave w owns gate rows j=16w+c for r (row j),
// z (row 128+j), n (row 256+j); lane c owns hidden unit j, quads redundant.
//
// R12 = R10 (proven, 211 us) + ONE delta: the x-projection GEMM is pipelined
// into the recurrence steps (ax ds_reads at s=0, one x-MFMA at s=1..6 placed
// AFTER the step's 12 MFMAs as matrix-pipe filler; results in regs; the chunk
// boundary only writes gxp from regs). The step-MFMA cluster, its C-operands,
// a-read order, gxh-as-VALU-adds, and the gate tail are BYTE-IDENTICAL to
// R10 — R9/R11 failures quarantined any edit to that cluster.
__global__ __launch_bounds__(NTHREADS, 2) void gru_r12(
    const float* __restrict__ x,      // (T*N, STATE)
    const float* __restrict__ h0,     // (N, HID)
    const float* __restrict__ masks,  // (T*N, 1) in {0,1}
    const float* __restrict__ wih,    // (3H, STATE)
    const float* __restrict__ whh,    // (3H, HID)
    const float* __restrict__ bih,    // (3H)
    const float* __restrict__ bhh,    // (3H)
    float* __restrict__ out)          // ys (T*N,H) then h_final (N,H)
{
    const int b    = blockIdx.x;
    const int tid  = threadIdx.x;
    const int w    = tid >> 6;
    const int lane = tid & 63;
    const int c    = lane & 15;
    const int quad = lane >> 4;
    const int j    = 16 * w + c;            // owned hidden unit (0..127)

    __shared__ __align__(16) _Float16 buf[2][HID];        // masked h f16, step parity
    __shared__ __align__(16) _Float16 xh[2][16][XPAD];    // x f16 per chunk (padded rows)
    __shared__ __align__(16) float    gxp[16][HID][4];    // gx+bias (exp2-scaled): [step][unit][{r,z,n,pad}] f32

    const float SRZ = -1.44269504088896341f;   // -log2(e)
    const float SN  = -2.88539008177792681f;   // -2*log2(e)
    const float scl[3] = { SRZ, SRZ, SN };

    // ---- persistent W_hh B-fragments (K=128 -> 4 chunks), exp2-pre-scaled ----
    const int rowb[3] = { j, HID + j, 2 * HID + j };
    half8 Bh[3][4];
#pragma unroll
    for (int ti = 0; ti < 3; ++ti) {
        const int g = rowb[ti];
        const float sc = scl[ti];
#pragma unroll
        for (int kt = 0; kt < 4; ++kt) {
            const float* src = whh + (size_t)g * HID + kt * 32 + quad * 8;
            const float4 p0 = *(const float4*)(src);
            const float4 p1 = *(const float4*)(src + 4);
            half8 hb;
            hb[0] = (_Float16)(sc * p0.x); hb[1] = (_Float16)(sc * p0.y);
            hb[2] = (_Float16)(sc * p0.z); hb[3] = (_Float16)(sc * p0.w);
            hb[4] = (_Float16)(sc * p1.x); hb[5] = (_Float16)(sc * p1.y);
            hb[6] = (_Float16)(sc * p1.z); hb[7] = (_Float16)(sc * p1.w);
            Bh[ti][kt] = hb;
        }
    }
    // ---- persistent W_ih B-fragments (K=64 -> 2 chunks), exp2-pre-scaled ----
    half8 Bx[3][2];
#pragma unroll
    for (int ti = 0; ti < 3; ++ti) {
        const int g = rowb[ti];
        const float sc = scl[ti];
#pragma unroll
        for (int kt = 0; kt < 2; ++kt) {
            const float* src = wih + (size_t)g * STATE + kt * 32 + quad * 8;
            const float4 p0 = *(const float4*)(src);
            const float4 p1 = *(const float4*)(src + 4);
            half8 hb;
            hb[0] = (_Float16)(sc * p0.x); hb[1] = (_Float16)(sc * p0.y);
            hb[2] = (_Float16)(sc * p0.z); hb[3] = (_Float16)(sc * p0.w);
            hb[4] = (_Float16)(sc * p1.x); hb[5] = (_Float16)(sc * p1.y);
            hb[6] = (_Float16)(sc * p1.z); hb[7] = (_Float16)(sc * p1.w);
            Bx[ti][kt] = hb;
        }
    }

    // scaled biases (exp2 domain)
    const float br  = SRZ * (bih[j] + bhh[j]);
    const float bz  = SRZ * (bih[HID + j] + bhh[HID + j]);
    const float bxn = SN  * bih[2 * HID + j];
    const float bhn = SN  * bhh[2 * HID + j];

    const floatx4 zero4 = {0.f, 0.f, 0.f, 0.f};
    floatx4 cbhn = zero4; cbhn[0] = bhn;   // loop-invariant C-in for n chain

    // ---- state / staging init ----
    float hr = h0[(size_t)b * HID + j];
    float hm = masks[b] * hr;
    if (quad == 0) buf[0][j] = (_Float16)hm;

    float4 xp = {0.f, 0.f, 0.f, 0.f};
    if (tid < 256) {   // xh[0] = x steps 0..15 ; xp = x steps 16..31
        const int k = tid >> 4, cc = (tid & 15) * 4;
        const float4 xv = *(const float4*)(x + ((size_t)k * N_ENVS + b) * STATE + cc);
        half4_t hx = {(_Float16)xv.x, (_Float16)xv.y, (_Float16)xv.z, (_Float16)xv.w};
        *(half4_t*)&xh[0][k][cc] = hx;
        xp = *(const float4*)(x + ((size_t)(16 + k) * N_ENVS + b) * STATE + cc);
    }
    // mask windows: lane l holds masks[tb+1+l] for current chunk (l = lane&15)
    float mwin     = masks[(size_t)(1  + (lane & 15)) * N_ENVS + b];
    float mwin_nxt = masks[(size_t)(17 + (lane & 15)) * N_ENVS + b];

    float o[4] = {0.f, 0.f, 0.f, 0.f};   // output regs: step s=quad*4+i -> o[i]

    // x-projection result regs for the NEXT chunk (computed in-step, s=1..6)
    floatx4 xg0, xg1, xg2;
    half8 axp0, axp1;

    BAR();   // xh[0] + buf[0] visible

    // ---- prologue: x-GEMM for chunk 0 from xh[0] -> gxp (R10 boundary code) ----
    {
        const _Float16* xr = &xh[0][c][0];
        half8 ax0 = *(const half8*)&xr[quad * 8];
        half8 ax1 = *(const half8*)&xr[32 + quad * 8];
        floatx4 g0 = __builtin_amdgcn_mfma_f32_16x16x32_f16(ax0, Bx[0][0], zero4, 0, 0, 0);
        floatx4 g1 = __builtin_amdgcn_mfma_f32_16x16x32_f16(ax0, Bx[1][0], zero4, 0, 0, 0);
        floatx4 g2 = __builtin_amdgcn_mfma_f32_16x16x32_f16(ax0, Bx[2][0], zero4, 0, 0, 0);
        g0 = __builtin_amdgcn_mfma_f32_16x16x32_f16(ax1, Bx[0][1], g0, 0, 0, 0);
        g1 = __builtin_amdgcn_mfma_f32_16x16x32_f16(ax1, Bx[1][1], g1, 0, 0, 0);
        g2 = __builtin_amdgcn_mfma_f32_16x16x32_f16(ax1, Bx[2][1], g2, 0, 0, 0);
#pragma unroll
        for (int i = 0; i < 4; ++i) {
            floatx4 p;
            p[0] = g0[i] + br;
            p[1] = g1[i] + bz;
            p[2] = g2[i] + bxn;
            p[3] = 0.f;
            *(floatx4*)&gxp[quad * 4 + i][j][0] = p;
        }
    }

    for (int tc = 0; tc < 32; ++tc) {
        // ======== chunk boundary (once per 16 steps) ========
        if (tc > 0) {   // store previous chunk's outputs straight from registers
            const int tbp = (tc - 1) * 16;
#pragma unroll
            for (int i = 0; i < 4; ++i)
                out[((size_t)(tbp + quad * 4 + i) * N_ENVS + b) * HID + j] = o[i];
            // roll mask window
            mwin = mwin_nxt;
            const int stm = (tc + 1) * 16 + 1 + (lane & 15);
            mwin_nxt = masks[(size_t)(stm < T_STEPS ? stm : T_STEPS - 1) * N_ENVS + b];
            // gxp for this chunk from regs (x-MFMAs ran during previous chunk)
#pragma unroll
            for (int i = 0; i < 4; ++i) {
                floatx4 p;
                p[0] = xg0[i] + br;
                p[1] = xg1[i] + bz;
                p[2] = xg2[i] + bxn;
                p[3] = 0.f;
                *(floatx4*)&gxp[quad * 4 + i][j][0] = p;
            }
        }
        if (tid < 256) {   // xp (steps (tc+1)*16..+15) -> xh for next chunk
            const int k = tid >> 4, cc = (tid & 15) * 4;
            half4_t hx = {(_Float16)xp.x, (_Float16)xp.y, (_Float16)xp.z, (_Float16)xp.w};
            *(half4_t*)&xh[(tc + 1) & 1][k][cc] = hx;
            const int st = (tc + 2) * 16 + k;
            if (st < T_STEPS)
                xp = *(const float4*)(x + ((size_t)st * N_ENVS + b) * STATE + cc);
        }
        BAR();   // gxp + xh[(tc+1)&1] visible

        // ======== 16 recurrence steps, one barrier each ========
#pragma unroll
        for (int s = 0; s < 16; ++s) {
            const _Float16* bufc = buf[s & 1];
            _Float16* bufn = (_Float16*)buf[(s + 1) & 1];

            // A fragments: broadcast masked h (4 K-chunks of 32) — R10 order
            half8 a0 = *(const half8*)(bufc + 0 * 32 + quad * 8);
            half8 a1 = *(const half8*)(bufc + 1 * 32 + quad * 8);
            half8 a2 = *(const half8*)(bufc + 2 * 32 + quad * 8);
            half8 a3 = *(const half8*)(bufc + 3 * 32 + quad * 8);
            // x-gate terms: one b128 per lane (broadcast across quads), f32
            const floatx4 gxh = *(const floatx4*)&gxp[s][j][0];
            // masks[t+1], wave-uniform (window register always in-bounds)
            const float mn = __int_as_float(__builtin_amdgcn_readlane(__float_as_int(mwin), s));

            // ax fragments for the NEXT chunk's x-GEMM (xh[(tc+1)&1] staged at
            // this chunk's boundary, stable until boundary tc+2)
            if (s == 0) {
                const _Float16* xr = &xh[(tc + 1) & 1][c][0];
                axp0 = *(const half8*)&xr[quad * 8];
                axp1 = *(const half8*)&xr[32 + quad * 8];
            }

            // 12 MFMAs, 6 independent streams of depth 2 (R10 order, R10 C-ins)
            floatx4 r_a = __builtin_amdgcn_mfma_f32_16x16x32_f16(a0, Bh[0][0], zero4, 0, 0, 0);
            floatx4 r_b = __builtin_amdgcn_mfma_f32_16x16x32_f16(a2, Bh[0][2], zero4, 0, 0, 0);
            floatx4 z_a = __builtin_amdgcn_mfma_f32_16x16x32_f16(a0, Bh[1][0], zero4, 0, 0, 0);
            floatx4 z_b = __builtin_amdgcn_mfma_f32_16x16x32_f16(a2, Bh[1][2], zero4, 0, 0, 0);
            floatx4 n_a = __builtin_amdgcn_mfma_f32_16x16x32_f16(a0, Bh[2][0], cbhn,  0, 0, 0);
            floatx4 n_b = __builtin_amdgcn_mfma_f32_16x16x32_f16(a2, Bh[2][2], zero4, 0, 0, 0);
            r_a = __builtin_amdgcn_mfma_f32_16x16x32_f16(a1, Bh[0][1], r_a, 0, 0, 0);
            r_b = __builtin_amdgcn_mfma_f32_16x16x32_f16(a3, Bh[0][3], r_b, 0, 0, 0);
            z_a = __builtin_amdgcn_mfma_f32_16x16x32_f16(a1, Bh[1][1], z_a, 0, 0, 0);
            z_b = __builtin_amdgcn_mfma_f32_16x16x32_f16(a3, Bh[1][3], z_b, 0, 0, 0);
            n_a = __builtin_amdgcn_mfma_f32_16x16x32_f16(a1, Bh[2][1], n_a, 0, 0, 0);
            n_b = __builtin_amdgcn_mfma_f32_16x16x32_f16(a3, Bh[2][3], n_b, 0, 0, 0);

            // one x-MFMA per step s=1..6: matrix-pipe filler during the VALU
            // tail; off the critical issue path (after the 12 step MFMAs)
            if (s == 1) xg0 = __builtin_amdgcn_mfma_f32_16x16x32_f16(axp0, Bx[0][0], zero4, 0, 0, 0);
            if (s == 2) xg1 = __builtin_amdgcn_mfma_f32_16x16x32_f16(axp0, Bx[1][0], zero4, 0, 0, 0);
            if (s == 3) xg2 = __builtin_amdgcn_mfma_f32_16x16x32_f16(axp0, Bx[2][0], zero4, 0, 0, 0);
            if (s == 4) xg0 = __builtin_amdgcn_mfma_f32_16x16x32_f16(axp1, Bx[0][1], xg0, 0, 0, 0);
            if (s == 5) xg1 = __builtin_amdgcn_mfma_f32_16x16x32_f16(axp1, Bx[1][1], xg1, 0, 0, 0);
            if (s == 6) xg2 = __builtin_amdgcn_mfma_f32_16x16x32_f16(axp1, Bx[2][1], xg2, 0, 0, 0);

            // all terms in the exp2 domain (scaled by -log2e / -2log2e)
            const float urp = (r_a[0] + r_b[0]) + gxh[0];
            const float uzp = (z_a[0] + z_b[0]) + gxh[1];
            const float hnp = n_a[0] + n_b[0];              // incl. bhn (C-in)
            const float xnp = gxh[2];

            // gate math, 3 exp + 2 rcp (R10 tail, unchanged):
            const float e_r = fexp2(urp);                        // inf-safe: rcp(inf)=0
            const float rg  = __builtin_amdgcn_rcpf(1.f + e_r);
            const float ap  = fmaf(rg, hnp, xnp);
            const float e_t = fexp2_nabs(ap);                    // 2^(-|ap|), (0,1]
            const float e_z = fexp2(fminf(uzp, 43.28f));         // <= 2^43.28 = e^30, finite
            const float opt = 1.f + e_t;
            const float num = fmaf(hm, opt, -copysignf(e_z * (1.f - e_t), ap));
            const float hnew = num * __builtin_amdgcn_rcpf(opt * (1.f + e_z));

            hm = mn * hnew;                                      // write LDS ASAP
            if (quad == 0) bufn[j] = (_Float16)hm;               // masked h for next step
            o[s & 3] = (quad == (s >> 2)) ? hnew : o[s & 3];     // quad-striped output regs
            if (s == 15) hr = hnew;                              // only last step matters
            BAR();
        }
    }

    // final flush: chunk 31 from registers
    {
        const int tbp = 31 * 16;
#pragma unroll
        for (int i = 0; i < 4; ++i)
            out[((size_t)(tbp + quad * 4 + i) * N_ENVS + b) * HID + j] = o[i];
    }
    if (quad == 0)
        out[(size_t)T_STEPS * N_ENVS * HID + (size_t)b * HID + j] = hr;
}

extern "C" void kernel_launch(void* const* d_in, const int* in_sizes, int n_in,
                              void* d_out, int out_size, void* d_ws, size_t ws_size,
                              hipStream_t stream) {
    const float* x   = (const float*)d_in[0];
    const float* h0  = (const float*)d_in[1];
    const float* mk  = (const float*)d_in[2];
    const float* wih = (const float*)d_in[3];
    const float* whh = (const float*)d_in[4];
    const float* bih = (const float*)d_in[5];
    const float* bhh = (const float*)d_in[6];
    float* out = (float*)d_out;

    hipLaunchKernelGGL(gru_r12, dim3(N_ENVS), dim3(NTHREADS), 0, stream,
                       x, h0, mk, wih, whh, bih, bhh, out);
}

// Round 7
// 280.237 us; speedup vs baseline: 1.0058x; 1.0058x over previous
//
#include <hip/hip_runtime.h>
#include <math.h>

#define T_STEPS  512
#define N_ENVS   256
#define STATE    64
#define HID      128
#define NTHREADS 512   // 8 waves
#define XPAD     72    // xh row stride in f16 (64 + 8 pad: breaks 16-way bank conflict)

typedef _Float16 half8   __attribute__((ext_vector_type(8)));
typedef _Float16 half4_t __attribute__((ext_vector_type(4)));
typedef float    floatx4 __attribute__((ext_vector_type(4)));

// Raw workgroup barrier: LDS visibility only (lgkmcnt), NO vmcnt/expcnt drain.
#define BAR() asm volatile("s_waitcnt lgkmcnt(0)\n\ts_barrier" ::: "memory")

// v_exp_f32 is natively 2^x. Weights are pre-scaled into the exp2 domain.
__device__ __forceinline__ float fexp2(float v) {
    float r;
    asm("v_exp_f32 %0, %1" : "=v"(r) : "v"(v));
    return r;
}
// 2^(-|v|) with free source modifiers (no explicit neg/abs VALU op).
__device__ __forceinline__ float fexp2_nabs(float v) {
    float r;
    asm("v_exp_f32 %0, -|%1|" : "=v"(r) : "v"(v));
    return r;
}

// One block per env, 8 waves. Wave w owns gate rows j=16w+c for r (row j),
// z (row 128+j), n (row 256+j); lane c owns hidden unit j, quads redundant.
//
// R13 = R10 (proven, 211 us; R12's in-step x-MFMA pipeline reverted: -10 us)
// + two deltas that avoid the quarantined step-MFMA cluster operand/order:
//  - mask-deferral (EXACT for masks in {0,1}): buf holds RAW hnew; mask is
//    applied post-MFMA via fma(mn, dot, gx) (same chain depth as the old add)
//    and hm = mn*hr at step START (off-spine). Removes the hm=mn*hnew mul
//    from the spine's write path. n C-in reverts to zero4 (R7-proven form),
//    bhn applied in the same fma.
//  - boundary ax-read hoist: next chunk's x-fragment ds_reads issue at s==15
//    (xh stable all chunk); boundary x-GEMM starts without the ~120-cyc read
//    wait. Chunk-0 gxp via prologue (R12's placement, proven passing).
__global__ __launch_bounds__(NTHREADS, 2) void gru_r13(
    const float* __restrict__ x,      // (T*N, STATE)
    const float* __restrict__ h0,     // (N, HID)
    const float* __restrict__ masks,  // (T*N, 1) in {0,1}
    const float* __restrict__ wih,    // (3H, STATE)
    const float* __restrict__ whh,    // (3H, HID)
    const float* __restrict__ bih,    // (3H)
    const float* __restrict__ bhh,    // (3H)
    float* __restrict__ out)          // ys (T*N,H) then h_final (N,H)
{
    const int b    = blockIdx.x;
    const int tid  = threadIdx.x;
    const int w    = tid >> 6;
    const int lane = tid & 63;
    const int c    = lane & 15;
    const int quad = lane >> 4;
    const int j    = 16 * w + c;            // owned hidden unit (0..127)

    __shared__ __align__(16) _Float16 buf[2][HID];        // RAW h f16, step parity
    __shared__ __align__(16) _Float16 xh[2][16][XPAD];    // x f16 per chunk (padded rows)
    __shared__ __align__(16) float    gxp[16][HID][4];    // gx+bias (exp2-scaled): [step][unit][{r,z,n,pad}] f32

    const float SRZ = -1.44269504088896341f;   // -log2(e)
    const float SN  = -2.88539008177792681f;   // -2*log2(e)
    const float scl[3] = { SRZ, SRZ, SN };

    // ---- persistent W_hh B-fragments (K=128 -> 4 chunks), exp2-pre-scaled ----
    const int rowb[3] = { j, HID + j, 2 * HID + j };
    half8 Bh[3][4];
#pragma unroll
    for (int ti = 0; ti < 3; ++ti) {
        const int g = rowb[ti];
        const float sc = scl[ti];
#pragma unroll
        for (int kt = 0; kt < 4; ++kt) {
            const float* src = whh + (size_t)g * HID + kt * 32 + quad * 8;
            const float4 p0 = *(const float4*)(src);
            const float4 p1 = *(const float4*)(src + 4);
            half8 hb;
            hb[0] = (_Float16)(sc * p0.x); hb[1] = (_Float16)(sc * p0.y);
            hb[2] = (_Float16)(sc * p0.z); hb[3] = (_Float16)(sc * p0.w);
            hb[4] = (_Float16)(sc * p1.x); hb[5] = (_Float16)(sc * p1.y);
            hb[6] = (_Float16)(sc * p1.z); hb[7] = (_Float16)(sc * p1.w);
            Bh[ti][kt] = hb;
        }
    }
    // ---- persistent W_ih B-fragments (K=64 -> 2 chunks), exp2-pre-scaled ----
    half8 Bx[3][2];
#pragma unroll
    for (int ti = 0; ti < 3; ++ti) {
        const int g = rowb[ti];
        const float sc = scl[ti];
#pragma unroll
        for (int kt = 0; kt < 2; ++kt) {
            const float* src = wih + (size_t)g * STATE + kt * 32 + quad * 8;
            const float4 p0 = *(const float4*)(src);
            const float4 p1 = *(const float4*)(src + 4);
            half8 hb;
            hb[0] = (_Float16)(sc * p0.x); hb[1] = (_Float16)(sc * p0.y);
            hb[2] = (_Float16)(sc * p0.z); hb[3] = (_Float16)(sc * p0.w);
            hb[4] = (_Float16)(sc * p1.x); hb[5] = (_Float16)(sc * p1.y);
            hb[6] = (_Float16)(sc * p1.z); hb[7] = (_Float16)(sc * p1.w);
            Bx[ti][kt] = hb;
        }
    }

    // scaled biases (exp2 domain)
    const float br  = SRZ * (bih[j] + bhh[j]);
    const float bz  = SRZ * (bih[HID + j] + bhh[HID + j]);
    const float bxn = SN  * bih[2 * HID + j];
    const float bhn = SN  * bhh[2 * HID + j];

    const floatx4 zero4 = {0.f, 0.f, 0.f, 0.f};

    // ---- state / staging init ----
    float hr = h0[(size_t)b * HID + j];     // RAW h (mask applied in-step)
    if (quad == 0) buf[0][j] = (_Float16)hr;

    float4 xp = {0.f, 0.f, 0.f, 0.f};
    if (tid < 256) {   // xh[0] = x steps 0..15 ; xp = x steps 16..31
        const int k = tid >> 4, cc = (tid & 15) * 4;
        const float4 xv = *(const float4*)(x + ((size_t)k * N_ENVS + b) * STATE + cc);
        half4_t hx = {(_Float16)xv.x, (_Float16)xv.y, (_Float16)xv.z, (_Float16)xv.w};
        *(half4_t*)&xh[0][k][cc] = hx;
        xp = *(const float4*)(x + ((size_t)(16 + k) * N_ENVS + b) * STATE + cc);
    }
    // mask windows: lane l holds masks[tb + l] for current chunk (l = lane&15)
    float mwin     = masks[(size_t)((lane & 15)) * N_ENVS + b];
    float mwin_nxt = masks[(size_t)(16 + (lane & 15)) * N_ENVS + b];

    float o[4] = {0.f, 0.f, 0.f, 0.f};   // output regs: step s=quad*4+i -> o[i]

    half8 axp0, axp1;   // hoisted x fragments for the NEXT chunk's boundary GEMM

    BAR();   // xh[0] + buf[0] visible

    // ---- prologue: x-GEMM for chunk 0 from xh[0] -> gxp ----
    {
        const _Float16* xr = &xh[0][c][0];
        half8 ax0 = *(const half8*)&xr[quad * 8];
        half8 ax1 = *(const half8*)&xr[32 + quad * 8];
        floatx4 g0 = __builtin_amdgcn_mfma_f32_16x16x32_f16(ax0, Bx[0][0], zero4, 0, 0, 0);
        floatx4 g1 = __builtin_amdgcn_mfma_f32_16x16x32_f16(ax0, Bx[1][0], zero4, 0, 0, 0);
        floatx4 g2 = __builtin_amdgcn_mfma_f32_16x16x32_f16(ax0, Bx[2][0], zero4, 0, 0, 0);
        g0 = __builtin_amdgcn_mfma_f32_16x16x32_f16(ax1, Bx[0][1], g0, 0, 0, 0);
        g1 = __builtin_amdgcn_mfma_f32_16x16x32_f16(ax1, Bx[1][1], g1, 0, 0, 0);
        g2 = __builtin_amdgcn_mfma_f32_16x16x32_f16(ax1, Bx[2][1], g2, 0, 0, 0);
#pragma unroll
        for (int i = 0; i < 4; ++i) {
            floatx4 p;
            p[0] = g0[i] + br;
            p[1] = g1[i] + bz;
            p[2] = g2[i] + bxn;
            p[3] = 0.f;
            *(floatx4*)&gxp[quad * 4 + i][j][0] = p;
        }
    }

    for (int tc = 0; tc < 32; ++tc) {
        // ======== chunk boundary (once per 16 steps) ========
        if (tc > 0) {   // store previous chunk's outputs straight from registers
            const int tbp = (tc - 1) * 16;
#pragma unroll
            for (int i = 0; i < 4; ++i)
                out[((size_t)(tbp + quad * 4 + i) * N_ENVS + b) * HID + j] = o[i];
            // roll mask window (lane l -> masks[tc*16 + l])
            mwin = mwin_nxt;
            const int stm = (tc + 1) * 16 + (lane & 15);
            mwin_nxt = masks[(size_t)(stm < T_STEPS ? stm : T_STEPS - 1) * N_ENVS + b];
            // x-GEMM for THIS chunk from hoisted fragments (no read wait)
            floatx4 g0 = __builtin_amdgcn_mfma_f32_16x16x32_f16(axp0, Bx[0][0], zero4, 0, 0, 0);
            floatx4 g1 = __builtin_amdgcn_mfma_f32_16x16x32_f16(axp0, Bx[1][0], zero4, 0, 0, 0);
            floatx4 g2 = __builtin_amdgcn_mfma_f32_16x16x32_f16(axp0, Bx[2][0], zero4, 0, 0, 0);
            g0 = __builtin_amdgcn_mfma_f32_16x16x32_f16(axp1, Bx[0][1], g0, 0, 0, 0);
            g1 = __builtin_amdgcn_mfma_f32_16x16x32_f16(axp1, Bx[1][1], g1, 0, 0, 0);
            g2 = __builtin_amdgcn_mfma_f32_16x16x32_f16(axp1, Bx[2][1], g2, 0, 0, 0);
#pragma unroll
            for (int i = 0; i < 4; ++i) {
                floatx4 p;
                p[0] = g0[i] + br;
                p[1] = g1[i] + bz;
                p[2] = g2[i] + bxn;
                p[3] = 0.f;
                *(floatx4*)&gxp[quad * 4 + i][j][0] = p;
            }
        }
        if (tid < 256) {   // xp (steps (tc+1)*16..+15) -> xh for next chunk
            const int k = tid >> 4, cc = (tid & 15) * 4;
            half4_t hx = {(_Float16)xp.x, (_Float16)xp.y, (_Float16)xp.z, (_Float16)xp.w};
            *(half4_t*)&xh[(tc + 1) & 1][k][cc] = hx;
            const int st = (tc + 2) * 16 + k;
            if (st < T_STEPS)
                xp = *(const float4*)(x + ((size_t)st * N_ENVS + b) * STATE + cc);
        }
        BAR();   // gxp + xh[(tc+1)&1] visible

        // ======== 16 recurrence steps, one barrier each ========
#pragma unroll
        for (int s = 0; s < 16; ++s) {
            const _Float16* bufc = buf[s & 1];
            _Float16* bufn = (_Float16*)buf[(s + 1) & 1];

            // A fragments: broadcast RAW h (4 K-chunks of 32) — R10 order
            half8 a0 = *(const half8*)(bufc + 0 * 32 + quad * 8);
            half8 a1 = *(const half8*)(bufc + 1 * 32 + quad * 8);
            half8 a2 = *(const half8*)(bufc + 2 * 32 + quad * 8);
            half8 a3 = *(const half8*)(bufc + 3 * 32 + quad * 8);
            // x-gate terms: one b128 per lane (broadcast across quads), f32
            const floatx4 gxh = *(const floatx4*)&gxp[s][j][0];
            // masks[t] for THIS step t = tc*16+s, wave-uniform
            const float mn = __int_as_float(__builtin_amdgcn_readlane(__float_as_int(mwin), s));
            // masked h term for the update — off-spine (overlaps ds_reads)
            const float hm = mn * hr;

            // hoist next chunk's x fragments at the last step (xh stable)
            if (s == 15) {
                const _Float16* xr = &xh[(tc + 1) & 1][c][0];
                axp0 = *(const half8*)&xr[quad * 8];
                axp1 = *(const half8*)&xr[32 + quad * 8];
            }

            // 12 MFMAs, 6 independent streams of depth 2 (R10 order; all C-ins
            // zero4 = R7-proven form; mask/bias applied post-MFMA via fma)
            floatx4 r_a = __builtin_amdgcn_mfma_f32_16x16x32_f16(a0, Bh[0][0], zero4, 0, 0, 0);
            floatx4 r_b = __builtin_amdgcn_mfma_f32_16x16x32_f16(a2, Bh[0][2], zero4, 0, 0, 0);
            floatx4 z_a = __builtin_amdgcn_mfma_f32_16x16x32_f16(a0, Bh[1][0], zero4, 0, 0, 0);
            floatx4 z_b = __builtin_amdgcn_mfma_f32_16x16x32_f16(a2, Bh[1][2], zero4, 0, 0, 0);
            floatx4 n_a = __builtin_amdgcn_mfma_f32_16x16x32_f16(a0, Bh[2][0], zero4, 0, 0, 0);
            floatx4 n_b = __builtin_amdgcn_mfma_f32_16x16x32_f16(a2, Bh[2][2], zero4, 0, 0, 0);
            r_a = __builtin_amdgcn_mfma_f32_16x16x32_f16(a1, Bh[0][1], r_a, 0, 0, 0);
            r_b = __builtin_amdgcn_mfma_f32_16x16x32_f16(a3, Bh[0][3], r_b, 0, 0, 0);
            z_a = __builtin_amdgcn_mfma_f32_16x16x32_f16(a1, Bh[1][1], z_a, 0, 0, 0);
            z_b = __builtin_amdgcn_mfma_f32_16x16x32_f16(a3, Bh[1][3], z_b, 0, 0, 0);
            n_a = __builtin_amdgcn_mfma_f32_16x16x32_f16(a1, Bh[2][1], n_a, 0, 0, 0);
            n_b = __builtin_amdgcn_mfma_f32_16x16x32_f16(a3, Bh[2][3], n_b, 0, 0, 0);

            // mask applied to the h-dots (exact: mn in {0,1}); same chain depth
            // as the old add (add -> fma). All terms in the exp2 domain.
            const float urp = fmaf(mn, r_a[0] + r_b[0], gxh[0]);
            const float uzp = fmaf(mn, z_a[0] + z_b[0], gxh[1]);
            const float hnp = fmaf(mn, n_a[0] + n_b[0], bhn);
            const float xnp = gxh[2];

            // gate math, 3 exp + 2 rcp (R10 tail; write path one mul shorter):
            const float e_r = fexp2(urp);                        // inf-safe: rcp(inf)=0
            const float rg  = __builtin_amdgcn_rcpf(1.f + e_r);
            const float ap  = fmaf(rg, hnp, xnp);
            const float e_t = fexp2_nabs(ap);                    // 2^(-|ap|), (0,1]
            const float e_z = fexp2(fminf(uzp, 43.28f));         // <= 2^43.28 = e^30, finite
            const float opt = 1.f + e_t;
            const float num = fmaf(hm, opt, -copysignf(e_z * (1.f - e_t), ap));
            const float hnew = num * __builtin_amdgcn_rcpf(opt * (1.f + e_z));

            if (quad == 0) bufn[j] = (_Float16)hnew;             // RAW h for next step
            o[s & 3] = (quad == (s >> 2)) ? hnew : o[s & 3];     // quad-striped output regs
            hr = hnew;                                           // feeds next step's hm
            BAR();
        }
    }

    // final flush: chunk 31 from registers
    {
        const int tbp = 31 * 16;
#pragma unroll
        for (int i = 0; i < 4; ++i)
            out[((size_t)(tbp + quad * 4 + i) * N_ENVS + b) * HID + j] = o[i];
    }
    if (quad == 0)
        out[(size_t)T_STEPS * N_ENVS * HID + (size_t)b * HID + j] = hr;
}

extern "C" void kernel_launch(void* const* d_in, const int* in_sizes, int n_in,
                              void* d_out, int out_size, void* d_ws, size_t ws_size,
                              hipStream_t stream) {
    const float* x   = (const float*)d_in[0];
    const float* h0  = (const float*)d_in[1];
    const float* mk  = (const float*)d_in[2];
    const float* wih = (const float*)d_in[3];
    const float* whh = (const float*)d_in[4];
    const float* bih = (const float*)d_in[5];
    const float* bhh = (const float*)d_in[6];
    float* out = (float*)d_out;

    hipLaunchKernelGGL(gru_r13, dim3(N_ENVS), dim3(NTHREADS), 0, stream,
                       x, h0, mk, wih, whh, bih, bhh, out);
}

// Round 8
// 277.817 us; speedup vs baseline: 1.0146x; 1.0087x over previous
//
#include <hip/hip_runtime.h>
#include <math.h>

#define T_STEPS  512
#define N_ENVS   256
#define STATE    64
#define HID      128
#define NTHREADS 512   // 8 waves
#define XPAD     72    // xh row stride in f16 (64 + 8 pad: breaks 16-way bank conflict)

typedef _Float16 half8   __attribute__((ext_vector_type(8)));
typedef _Float16 half4_t __attribute__((ext_vector_type(4)));
typedef float    floatx4 __attribute__((ext_vector_type(4)));

// Raw workgroup barrier: LDS visibility only (lgkmcnt), NO vmcnt/expcnt drain.
// __syncthreads() would drain vmcnt (HBM out-stores + x prefetch) at every
// step barrier; neither feeds LDS state.
#define BAR() asm volatile("s_waitcnt lgkmcnt(0)\n\ts_barrier" ::: "memory")

// v_exp_f32 is natively 2^x. Weights are pre-scaled into the exp2 domain.
__device__ __forceinline__ float fexp2(float v) {
    float r;
    asm("v_exp_f32 %0, %1" : "=v"(r) : "v"(v));
    return r;
}
// 2^(-|v|) with free source modifiers (no explicit neg/abs VALU op).
__device__ __forceinline__ float fexp2_nabs(float v) {
    float r;
    asm("v_exp_f32 %0, -|%1|" : "=v"(r) : "v"(v));
    return r;
}

// One block per env, 8 waves. Wave w owns gate rows j=16w+c for r (row j),
// z (row 128+j), n (row 256+j); lane c owns hidden unit j, quads redundant.
//
// R14 = R10 byte-identical (session best: 211 us kernel). Six rounds of
// structural exploration around this point:
//  - R8 (bpermute gx distribution): +9 us — exposed serial LDS-pipe time
//  - R9 (MFMA reorder + tail re-assoc): FAILED — quarantined
//  - R11 (gxh via MFMA C-in): FAILED — quarantined
//  - R12 (in-step x-GEMM pipeline): +10 us — perturbed step schedule
//  - R13 (mask-deferral + ax hoist): +8 us — perturbed step schedule
// Conclusion: the step spine (LDS h-exchange RT ~120-140cy + 12-MFMA chain
// ~60-80cy + gate VALU/exp chain ~60-80cy, one barrier/step x 512 serial
// steps) is at its measured floor for this structure; only pure dependent-op
// removals ever won, and those are exhausted.
__global__ __launch_bounds__(NTHREADS, 2) void gru_r14(
    const float* __restrict__ x,      // (T*N, STATE)
    const float* __restrict__ h0,     // (N, HID)
    const float* __restrict__ masks,  // (T*N, 1) in {0,1}
    const float* __restrict__ wih,    // (3H, STATE)
    const float* __restrict__ whh,    // (3H, HID)
    const float* __restrict__ bih,    // (3H)
    const float* __restrict__ bhh,    // (3H)
    float* __restrict__ out)          // ys (T*N,H) then h_final (N,H)
{
    const int b    = blockIdx.x;
    const int tid  = threadIdx.x;
    const int w    = tid >> 6;
    const int lane = tid & 63;
    const int c    = lane & 15;
    const int quad = lane >> 4;
    const int j    = 16 * w + c;            // owned hidden unit (0..127)

    __shared__ __align__(16) _Float16 buf[2][HID];        // masked h f16, step parity
    __shared__ __align__(16) _Float16 xh[2][16][XPAD];    // x f16 per chunk (padded rows)
    __shared__ __align__(16) float    gxp[16][HID][4];    // gx+bias (exp2-scaled): [step][unit][{r,z,n,pad}] f32

    const float SRZ = -1.44269504088896341f;   // -log2(e)
    const float SN  = -2.88539008177792681f;   // -2*log2(e)
    const float scl[3] = { SRZ, SRZ, SN };

    // ---- persistent W_hh B-fragments (K=128 -> 4 chunks), exp2-pre-scaled ----
    const int rowb[3] = { j, HID + j, 2 * HID + j };
    half8 Bh[3][4];
#pragma unroll
    for (int ti = 0; ti < 3; ++ti) {
        const int g = rowb[ti];
        const float sc = scl[ti];
#pragma unroll
        for (int kt = 0; kt < 4; ++kt) {
            const float* src = whh + (size_t)g * HID + kt * 32 + quad * 8;
            const float4 p0 = *(const float4*)(src);
            const float4 p1 = *(const float4*)(src + 4);
            half8 hb;
            hb[0] = (_Float16)(sc * p0.x); hb[1] = (_Float16)(sc * p0.y);
            hb[2] = (_Float16)(sc * p0.z); hb[3] = (_Float16)(sc * p0.w);
            hb[4] = (_Float16)(sc * p1.x); hb[5] = (_Float16)(sc * p1.y);
            hb[6] = (_Float16)(sc * p1.z); hb[7] = (_Float16)(sc * p1.w);
            Bh[ti][kt] = hb;
        }
    }
    // ---- persistent W_ih B-fragments (K=64 -> 2 chunks), exp2-pre-scaled ----
    half8 Bx[3][2];
#pragma unroll
    for (int ti = 0; ti < 3; ++ti) {
        const int g = rowb[ti];
        const float sc = scl[ti];
#pragma unroll
        for (int kt = 0; kt < 2; ++kt) {
            const float* src = wih + (size_t)g * STATE + kt * 32 + quad * 8;
            const float4 p0 = *(const float4*)(src);
            const float4 p1 = *(const float4*)(src + 4);
            half8 hb;
            hb[0] = (_Float16)(sc * p0.x); hb[1] = (_Float16)(sc * p0.y);
            hb[2] = (_Float16)(sc * p0.z); hb[3] = (_Float16)(sc * p0.w);
            hb[4] = (_Float16)(sc * p1.x); hb[5] = (_Float16)(sc * p1.y);
            hb[6] = (_Float16)(sc * p1.z); hb[7] = (_Float16)(sc * p1.w);
            Bx[ti][kt] = hb;
        }
    }

    // scaled biases (exp2 domain)
    const float br  = SRZ * (bih[j] + bhh[j]);
    const float bz  = SRZ * (bih[HID + j] + bhh[HID + j]);
    const float bxn = SN  * bih[2 * HID + j];
    const float bhn = SN  * bhh[2 * HID + j];

    const floatx4 zero4 = {0.f, 0.f, 0.f, 0.f};
    floatx4 cbhn = zero4; cbhn[0] = bhn;   // loop-invariant C-in for n chain

    // ---- state / staging init ----
    float hr = h0[(size_t)b * HID + j];
    float hm = masks[b] * hr;
    if (quad == 0) buf[0][j] = (_Float16)hm;

    float4 xp = {0.f, 0.f, 0.f, 0.f};
    if (tid < 256) {   // xh[0] = x steps 0..15 ; xp = x steps 16..31
        const int k = tid >> 4, cc = (tid & 15) * 4;
        const float4 xv = *(const float4*)(x + ((size_t)k * N_ENVS + b) * STATE + cc);
        half4_t hx = {(_Float16)xv.x, (_Float16)xv.y, (_Float16)xv.z, (_Float16)xv.w};
        *(half4_t*)&xh[0][k][cc] = hx;
        xp = *(const float4*)(x + ((size_t)(16 + k) * N_ENVS + b) * STATE + cc);
    }
    // mask windows: lane l holds masks[tb+1+l] for current chunk (l = lane&15)
    float mwin     = masks[(size_t)(1  + (lane & 15)) * N_ENVS + b];
    float mwin_nxt = masks[(size_t)(17 + (lane & 15)) * N_ENVS + b];

    float o[4] = {0.f, 0.f, 0.f, 0.f};   // output regs: step s=quad*4+i -> o[i]

    BAR();   // xh[0] + buf[0] visible

    for (int tc = 0; tc < 32; ++tc) {
        // ======== chunk boundary (once per 16 steps) ========
        if (tc > 0) {   // store previous chunk's outputs straight from registers
            const int tbp = (tc - 1) * 16;
#pragma unroll
            for (int i = 0; i < 4; ++i)
                out[((size_t)(tbp + quad * 4 + i) * N_ENVS + b) * HID + j] = o[i];
            // roll mask window
            mwin = mwin_nxt;
            const int stm = (tc + 1) * 16 + 1 + (lane & 15);
            mwin_nxt = masks[(size_t)(stm < T_STEPS ? stm : T_STEPS - 1) * N_ENVS + b];
        }
        if (tid < 256) {   // xp (steps (tc+1)*16..+15) -> xh for next chunk
            const int k = tid >> 4, cc = (tid & 15) * 4;
            half4_t hx = {(_Float16)xp.x, (_Float16)xp.y, (_Float16)xp.z, (_Float16)xp.w};
            *(half4_t*)&xh[(tc + 1) & 1][k][cc] = hx;
            const int st = (tc + 2) * 16 + k;
            if (st < T_STEPS)
                xp = *(const float4*)(x + ((size_t)st * N_ENVS + b) * STATE + cc);
        }

        // batched x-projection GEMM for this chunk: A row m=c is x[step tb+c][*]
        {
            const _Float16* xr = &xh[tc & 1][c][0];
            half8 ax0 = *(const half8*)&xr[quad * 8];
            half8 ax1 = *(const half8*)&xr[32 + quad * 8];
            floatx4 g0 = __builtin_amdgcn_mfma_f32_16x16x32_f16(ax0, Bx[0][0], zero4, 0, 0, 0);
            floatx4 g1 = __builtin_amdgcn_mfma_f32_16x16x32_f16(ax0, Bx[1][0], zero4, 0, 0, 0);
            floatx4 g2 = __builtin_amdgcn_mfma_f32_16x16x32_f16(ax0, Bx[2][0], zero4, 0, 0, 0);
            g0 = __builtin_amdgcn_mfma_f32_16x16x32_f16(ax1, Bx[0][1], g0, 0, 0, 0);
            g1 = __builtin_amdgcn_mfma_f32_16x16x32_f16(ax1, Bx[1][1], g1, 0, 0, 0);
            g2 = __builtin_amdgcn_mfma_f32_16x16x32_f16(ax1, Bx[2][1], g2, 0, 0, 0);
            // D[step=quad*4+i][col=c] -> f32 {r,z,n,pad} with scaled biases folded
#pragma unroll
            for (int i = 0; i < 4; ++i) {
                floatx4 p;
                p[0] = g0[i] + br;
                p[1] = g1[i] + bz;
                p[2] = g2[i] + bxn;
                p[3] = 0.f;
                *(floatx4*)&gxp[quad * 4 + i][j][0] = p;
            }
        }
        BAR();

        // ======== 16 recurrence steps, one barrier each ========
#pragma unroll
        for (int s = 0; s < 16; ++s) {
            const _Float16* bufc = buf[s & 1];
            _Float16* bufn = (_Float16*)buf[(s + 1) & 1];

            // A fragments: broadcast masked h (4 K-chunks of 32)
            half8 a0 = *(const half8*)(bufc + 0 * 32 + quad * 8);
            half8 a1 = *(const half8*)(bufc + 1 * 32 + quad * 8);
            half8 a2 = *(const half8*)(bufc + 2 * 32 + quad * 8);
            half8 a3 = *(const half8*)(bufc + 3 * 32 + quad * 8);
            // x-gate terms: one b128 per lane (broadcast across quads), f32
            const floatx4 gxh = *(const floatx4*)&gxp[s][j][0];
            // masks[t+1], wave-uniform (window register always in-bounds)
            const float mn = __int_as_float(__builtin_amdgcn_readlane(__float_as_int(mwin), s));

            // 12 MFMAs, 6 independent streams of depth 2 (R7 order)
            floatx4 r_a = __builtin_amdgcn_mfma_f32_16x16x32_f16(a0, Bh[0][0], zero4, 0, 0, 0);
            floatx4 r_b = __builtin_amdgcn_mfma_f32_16x16x32_f16(a2, Bh[0][2], zero4, 0, 0, 0);
            floatx4 z_a = __builtin_amdgcn_mfma_f32_16x16x32_f16(a0, Bh[1][0], zero4, 0, 0, 0);
            floatx4 z_b = __builtin_amdgcn_mfma_f32_16x16x32_f16(a2, Bh[1][2], zero4, 0, 0, 0);
            floatx4 n_a = __builtin_amdgcn_mfma_f32_16x16x32_f16(a0, Bh[2][0], cbhn,  0, 0, 0);
            floatx4 n_b = __builtin_amdgcn_mfma_f32_16x16x32_f16(a2, Bh[2][2], zero4, 0, 0, 0);
            r_a = __builtin_amdgcn_mfma_f32_16x16x32_f16(a1, Bh[0][1], r_a, 0, 0, 0);
            r_b = __builtin_amdgcn_mfma_f32_16x16x32_f16(a3, Bh[0][3], r_b, 0, 0, 0);
            z_a = __builtin_amdgcn_mfma_f32_16x16x32_f16(a1, Bh[1][1], z_a, 0, 0, 0);
            z_b = __builtin_amdgcn_mfma_f32_16x16x32_f16(a3, Bh[1][3], z_b, 0, 0, 0);
            n_a = __builtin_amdgcn_mfma_f32_16x16x32_f16(a1, Bh[2][1], n_a, 0, 0, 0);
            n_b = __builtin_amdgcn_mfma_f32_16x16x32_f16(a3, Bh[2][3], n_b, 0, 0, 0);

            // all terms in the exp2 domain (scaled by -log2e / -2log2e)
            const float urp = (r_a[0] + r_b[0]) + gxh[0];
            const float uzp = (z_a[0] + z_b[0]) + gxh[1];
            const float hnp = n_a[0] + n_b[0];              // incl. bhn (C-in)
            const float xnp = gxh[2];

            // gate math, 3 exp + 2 rcp:
            // r = 1/(1+2^urp); ap = -2log2e*(xn + r*hn); e_t = 2^(-|ap|)
            // h' = [hm*(1+e_t) - copysign(e_z*(1-e_t), ap)] / [(1+e_t)*(1+e_z)]
            const float e_r = fexp2(urp);                        // inf-safe: rcp(inf)=0
            const float rg  = __builtin_amdgcn_rcpf(1.f + e_r);
            const float ap  = fmaf(rg, hnp, xnp);
            const float e_t = fexp2_nabs(ap);                    // 2^(-|ap|), (0,1]
            const float e_z = fexp2(fminf(uzp, 43.28f));         // <= 2^43.28 = e^30, finite
            const float opt = 1.f + e_t;
            const float num = fmaf(hm, opt, -copysignf(e_z * (1.f - e_t), ap));
            const float hnew = num * __builtin_amdgcn_rcpf(opt * (1.f + e_z));

            hm = mn * hnew;                                      // write LDS ASAP
            if (quad == 0) bufn[j] = (_Float16)hm;               // masked h for next step
            o[s & 3] = (quad == (s >> 2)) ? hnew : o[s & 3];     // quad-striped output regs
            if (s == 15) hr = hnew;                              // only last step matters
            BAR();
        }
    }

    // final flush: chunk 31 from registers
    {
        const int tbp = 31 * 16;
#pragma unroll
        for (int i = 0; i < 4; ++i)
            out[((size_t)(tbp + quad * 4 + i) * N_ENVS + b) * HID + j] = o[i];
    }
    if (quad == 0)
        out[(size_t)T_STEPS * N_ENVS * HID + (size_t)b * HID + j] = hr;
}

extern "C" void kernel_launch(void* const* d_in, const int* in_sizes, int n_in,
                              void* d_out, int out_size, void* d_ws, size_t ws_size,
                              hipStream_t stream) {
    const float* x   = (const float*)d_in[0];
    const float* h0  = (const float*)d_in[1];
    const float* mk  = (const float*)d_in[2];
    const float* wih = (const float*)d_in[3];
    const float* whh = (const float*)d_in[4];
    const float* bih = (const float*)d_in[5];
    const float* bhh = (const float*)d_in[6];
    float* out = (float*)d_out;

    hipLaunchKernelGGL(gru_r14, dim3(N_ENVS), dim3(NTHREADS), 0, stream,
                       x, h0, mk, wih, whh, bih, bhh, out);
}